// Round 3
// baseline (277.182 us; speedup 1.0000x reference)
//
#include <hip/hip_runtime.h>

#define NORIENT 8

// ---------------- forward: stride-2 5x5 conv, 1 -> 8 channels ----------------
// One thread computes a 2x2 output block for all 8 channels from a 7x7 patch.
__global__ void fwd_conv_kernel(const float* __restrict__ in, long in_img_stride,
                                const float* __restrict__ filt,
                                float* __restrict__ out,
                                int H, int W, int OH, int OW, int N) {
    int OH2 = OH >> 1, OW2 = OW >> 1;
    long idx = (long)blockIdx.x * blockDim.x + threadIdx.x;
    long total = (long)N * OH2 * OW2;
    if (idx >= total) return;
    int ox2 = (int)(idx % OW2);
    long t = idx / OW2;
    int oy2 = (int)(t % OH2);
    int n = (int)(t / OH2);

    const float* __restrict__ ip = in + (long)n * in_img_stride;
    int y0 = 4 * oy2 - 2, x0 = 4 * ox2 - 2;

    float patch[7][7];
#pragma unroll
    for (int i = 0; i < 7; ++i) {
        int y = y0 + i;
        bool vy = (y >= 0) & (y < H);
        const float* rowp = ip + (long)(vy ? y : 0) * W;
#pragma unroll
        for (int j = 0; j < 7; ++j) {
            int x = x0 + j;
            bool vx = (x >= 0) & (x < W);
            float v = rowp[vx ? x : 0];
            patch[i][j] = (vy & vx) ? v : 0.f;
        }
    }

    long cs = (long)OH * OW;
    long ob0 = (long)n * NORIENT * cs + (long)(2 * oy2) * OW + 2 * ox2;
#pragma unroll
    for (int c = 0; c < NORIENT; ++c) {
        const float* __restrict__ F = filt + c * 25;  // wave-uniform -> s_load
        float a00 = 0.f, a01 = 0.f, a10 = 0.f, a11 = 0.f;
#pragma unroll
        for (int i = 0; i < 5; ++i) {
#pragma unroll
            for (int j = 0; j < 5; ++j) {
                float wv = F[i * 5 + j];
                a00 = fmaf(patch[i][j],         wv, a00);
                a01 = fmaf(patch[i][j + 2],     wv, a01);
                a10 = fmaf(patch[i + 2][j],     wv, a10);
                a11 = fmaf(patch[i + 2][j + 2], wv, a11);
            }
        }
        long ob = ob0 + (long)c * cs;
        *(float2*)&out[ob]      = make_float2(a00, a01);
        *(float2*)&out[ob + OW] = make_float2(a10, a11);
    }
}

// ---------------- inverse: transposed conv, 8 -> 1 channel, stride 2 ----------------
// Polyphase, 4 coefficient sites per thread: thread owns (p, q0..q0+3) and
// computes the 2x8 output block. Per channel: 3x6 patch = 3 float4 + 6 edge
// scalars (9 VMEM for 4 sites). Branch-free borders via clamp + mask-multiply.
__global__ void inv_tconv_kernel(const float* __restrict__ rec, long rec_img_stride,
                                 const float* __restrict__ coef,
                                 const float* __restrict__ filt,
                                 float* __restrict__ out,
                                 int h, int w, int N) {
    int w4 = w >> 2;
    long idx = (long)blockIdx.x * blockDim.x + threadIdx.x;
    long total = (long)N * h * w4;
    if (idx >= total) return;
    int qb = (int)(idx % w4);
    long t = idx / w4;
    int p = (int)(t % h);
    int n = (int)(t / h);
    int q0 = qb << 2;

    const float* __restrict__ rp = rec + (long)n * rec_img_stride;
    const float* __restrict__ cp = coef + (long)n * (long)NORIENT * h * w;
    int cs = h * w;

    int off = p * w + q0;
    bool vm = p > 0, vp = p < h - 1, um = q0 > 0, up = q0 + 4 < w;
    int om = vm ? off - w : off;      // clamped row above
    int op = vp ? off + w : off;      // clamped row below
    int dm = um ? -1 : 0;             // left edge offset (clamped)
    int dp = up ? 4 : 3;              // right edge offset (clamped)
    float fm = vm ? 1.f : 0.f, fp_ = vp ? 1.f : 0.f;
    float gm = um ? 1.f : 0.f, gp = up ? 1.f : 0.f;
    float c_mm = fm * gm, c_mp = fm * gp, c_pm = fp_ * gm, c_pp = fp_ * gp;

    float acc[4][4];  // [site][o00,o01,o10,o11]
#pragma unroll
    for (int s = 0; s < 4; ++s)
#pragma unroll
        for (int o = 0; o < 4; ++o) acc[s][o] = 0.f;

    auto do_channel = [&](const float* __restrict__ src, const float* __restrict__ F) {
        float4 r0 = *(const float4*)(src + om);
        float4 r1 = *(const float4*)(src + off);
        float4 r2 = *(const float4*)(src + op);
        float e0m = src[om + dm],  e0p = src[om + dp];
        float e1m = src[off + dm], e1p = src[off + dp];
        float e2m = src[op + dm],  e2p = src[op + dp];

        float P[3][6];
        P[0][0] = e0m * c_mm; P[0][1] = r0.x * fm; P[0][2] = r0.y * fm;
        P[0][3] = r0.z * fm;  P[0][4] = r0.w * fm; P[0][5] = e0p * c_mp;
        P[1][0] = e1m * gm;   P[1][1] = r1.x;      P[1][2] = r1.y;
        P[1][3] = r1.z;       P[1][4] = r1.w;      P[1][5] = e1p * gp;
        P[2][0] = e2m * c_pm; P[2][1] = r2.x * fp_; P[2][2] = r2.y * fp_;
        P[2][3] = r2.z * fp_; P[2][4] = r2.w * fp_; P[2][5] = e2p * c_pp;

        // weights include the tconv flip: site out(2p+dy, 2q+dx) uses
        // F[(4+dy-2a)*5 + (4+dx-2b)] with patch v[a][b] (derived & verified R2).
#pragma unroll
        for (int a = 0; a < 3; ++a) {
#pragma unroll
            for (int b = 0; b < 3; ++b) {
                float w00 = F[(4 - 2 * a) * 5 + (4 - 2 * b)];
#pragma unroll
                for (int s = 0; s < 4; ++s)
                    acc[s][0] = fmaf(P[a][s + b], w00, acc[s][0]);
                if (b >= 1) {
                    float w01 = F[(4 - 2 * a) * 5 + (5 - 2 * b)];
#pragma unroll
                    for (int s = 0; s < 4; ++s)
                        acc[s][1] = fmaf(P[a][s + b], w01, acc[s][1]);
                }
                if (a >= 1) {
                    float w10 = F[(5 - 2 * a) * 5 + (4 - 2 * b)];
#pragma unroll
                    for (int s = 0; s < 4; ++s)
                        acc[s][2] = fmaf(P[a][s + b], w10, acc[s][2]);
                }
                if (a >= 1 && b >= 1) {
                    float w11 = F[(5 - 2 * a) * 5 + (5 - 2 * b)];
#pragma unroll
                    for (int s = 0; s < 4; ++s)
                        acc[s][3] = fmaf(P[a][s + b], w11, acc[s][3]);
                }
            }
        }
    };

    do_channel(rp, filt);
#pragma unroll
    for (int c = 1; c < NORIENT; ++c)
        do_channel(cp + (long)c * cs, filt + c * 25);

    int OW = w << 1;
    long ob = (long)n * 4 * (long)cs + (long)(2 * p) * OW + 2 * q0;
    *(float4*)(out + ob)          = make_float4(acc[0][0], acc[0][1], acc[1][0], acc[1][1]);
    *(float4*)(out + ob + 4)      = make_float4(acc[2][0], acc[2][1], acc[3][0], acc[3][1]);
    *(float4*)(out + ob + OW)     = make_float4(acc[0][2], acc[0][3], acc[1][2], acc[1][3]);
    *(float4*)(out + ob + OW + 4) = make_float4(acc[2][2], acc[2][3], acc[3][2], acc[3][3]);
}

extern "C" void kernel_launch(void* const* d_in, const int* in_sizes, int n_in,
                              void* d_out, int out_size, void* d_ws, size_t ws_size,
                              hipStream_t stream) {
    const float* x     = (const float*)d_in[0];
    const float* fwd_f = (const float*)d_in[1];
    const float* inv_f = (const float*)d_in[2];
    float* out = (float*)d_out;
    float* ws  = (float*)d_ws;

    const int N = 32;

    // workspace layout (floats) — all offsets multiples of 4 -> 16B aligned
    float* l4 = ws;                  // 32*8*256*256 = 16,777,216
    float* l3 = l4 + 16777216;       // 32*8*128*128 =  4,194,304
    float* l2 = l3 + 4194304;        // 32*8*64*64   =  1,048,576
    float* l1 = l2 + 1048576;        // 32*8*32*32   =    262,144
    float* r1 = l1 + 262144;         // 32*64*64     =    131,072
    float* r2 = r1 + 131072;         // 32*128*128   =    524,288
    float* r3 = r2 + 524288;         // 32*256*256   =  2,097,152

    dim3 blk(256);
    auto nblocks = [](long total) { return dim3((unsigned)((total + 255) / 256)); };

    // ---- forward transform (threads = N * OH/2 * OW/2) ----
    fwd_conv_kernel<<<nblocks(32L * 128 * 128), blk, 0, stream>>>(
        x, 512L * 512, fwd_f, l4, 512, 512, 256, 256, N);
    fwd_conv_kernel<<<nblocks(32L * 64 * 64), blk, 0, stream>>>(
        l4, 8L * 256 * 256, fwd_f, l3, 256, 256, 128, 128, N);
    fwd_conv_kernel<<<nblocks(32L * 32 * 32), blk, 0, stream>>>(
        l3, 8L * 128 * 128, fwd_f, l2, 128, 128, 64, 64, N);
    fwd_conv_kernel<<<nblocks(32L * 16 * 16), blk, 0, stream>>>(
        l2, 8L * 64 * 64, fwd_f, l1, 64, 64, 32, 32, N);

    // ---- inverse transform (threads = N * h * w/4) ----
    inv_tconv_kernel<<<nblocks(32L * 32 * 8), blk, 0, stream>>>(
        l1, 8L * 32 * 32, l1, inv_f, r1, 32, 32, N);
    inv_tconv_kernel<<<nblocks(32L * 64 * 16), blk, 0, stream>>>(
        r1, 64L * 64, l2, inv_f, r2, 64, 64, N);
    inv_tconv_kernel<<<nblocks(32L * 128 * 32), blk, 0, stream>>>(
        r2, 128L * 128, l3, inv_f, r3, 128, 128, N);
    inv_tconv_kernel<<<nblocks(32L * 256 * 64), blk, 0, stream>>>(
        r3, 256L * 256, l4, inv_f, out, 256, 256, N);
}

// Round 4
// 112.807 us; speedup vs baseline: 2.4571x; 2.4571x over previous
//
#include <hip/hip_runtime.h>

#define NORIENT 8

// XCD-aware block swizzle: dispatch d -> XCD d%8 (round-robin). Remap so each
// XCD gets a contiguous chunk of logical tiles (halo rows shared in its L2).
__device__ __forceinline__ unsigned xcd_swz(unsigned bid, unsigned nwg) {
    unsigned chunk = nwg >> 3;
    return (nwg & 7u) ? bid : (bid & 7u) * chunk + (bid >> 3);
}

// ---------------- forward: stride-2 5x5 conv, 1 -> 8 channels ----------------
// One thread computes a 2x2 output block for all 8 channels from a 7x7 patch.
__global__ void fwd_conv_kernel(const float* __restrict__ in, long in_img_stride,
                                const float* __restrict__ filt,
                                float* __restrict__ out,
                                int H, int W, int OH, int OW, int N) {
    int OH2 = OH >> 1, OW2 = OW >> 1;
    unsigned sb = xcd_swz(blockIdx.x, gridDim.x);
    long idx = (long)sb * blockDim.x + threadIdx.x;
    long total = (long)N * OH2 * OW2;
    if (idx >= total) return;
    int ox2 = (int)(idx % OW2);
    long t = idx / OW2;
    int oy2 = (int)(t % OH2);
    int n = (int)(t / OH2);

    const float* __restrict__ ip = in + (long)n * in_img_stride;
    int y0 = 4 * oy2 - 2, x0 = 4 * ox2 - 2;

    float patch[7][7];
#pragma unroll
    for (int i = 0; i < 7; ++i) {
        int y = y0 + i;
        bool vy = (y >= 0) & (y < H);
        const float* rowp = ip + (long)(vy ? y : 0) * W;
#pragma unroll
        for (int j = 0; j < 7; ++j) {
            int x = x0 + j;
            bool vx = (x >= 0) & (x < W);
            float v = rowp[vx ? x : 0];
            patch[i][j] = (vy & vx) ? v : 0.f;
        }
    }

    long cs = (long)OH * OW;
    long ob0 = (long)n * NORIENT * cs + (long)(2 * oy2) * OW + 2 * ox2;
#pragma unroll
    for (int c = 0; c < NORIENT; ++c) {
        const float* __restrict__ F = filt + c * 25;  // wave-uniform -> s_load
        float a00 = 0.f, a01 = 0.f, a10 = 0.f, a11 = 0.f;
#pragma unroll
        for (int i = 0; i < 5; ++i) {
#pragma unroll
            for (int j = 0; j < 5; ++j) {
                float wv = F[i * 5 + j];
                a00 = fmaf(patch[i][j],         wv, a00);
                a01 = fmaf(patch[i][j + 2],     wv, a01);
                a10 = fmaf(patch[i + 2][j],     wv, a10);
                a11 = fmaf(patch[i + 2][j + 2], wv, a11);
            }
        }
        long ob = ob0 + (long)c * cs;
        *(float2*)&out[ob]      = make_float2(a00, a01);
        *(float2*)&out[ob + OW] = make_float2(a10, a11);
    }
}

// ---------------- inverse: transposed conv, 8 -> 1 channel, stride 2 ----------------
// Thread owns a 2x2 block of coefficient sites (p in {2a0,2a0+1}, q in {2b0,2b0+1})
// and computes the 4x4 output block (rows 4a0..+3, cols 4b0..+3).
// Per channel: 4 patch rows x 3 aligned float2 loads (12 VMEM). Stores are 4x
// float4, lane-contiguous per instruction (byte offset 16*lane) — the pattern
// R2 proved keeps WRITE_SIZE == output size (R3's strided float4s caused 10x RMW).
__global__ void inv_tconv_kernel(const float* __restrict__ rec, long rec_img_stride,
                                 const float* __restrict__ coef,
                                 const float* __restrict__ filt,
                                 float* __restrict__ out,
                                 int h, int w, int N) {
    int h2 = h >> 1, w2 = w >> 1;
    unsigned sb = xcd_swz(blockIdx.x, gridDim.x);
    long idx = (long)sb * blockDim.x + threadIdx.x;
    long total = (long)N * h2 * w2;
    if (idx >= total) return;
    int b0 = (int)(idx % w2);
    long t = idx / w2;
    int a0 = (int)(t % h2);
    int n = (int)(t / h2);

    const float* __restrict__ rp = rec + (long)n * rec_img_stride;
    const float* __restrict__ cp = coef + (long)n * (long)NORIENT * h * w;
    int cs = h * w;

    // patch rows 2a0-1 .. 2a0+2 (clamped), cols 2b0-1 .. 2b0+2 (clamped)
    bool fmv = a0 > 0, fpv = a0 < h2 - 1;
    bool um = b0 > 0, up = b0 < w2 - 1;
    float fm = fmv ? 1.f : 0.f, fp_ = fpv ? 1.f : 0.f;
    int r0 = (fmv ? 2 * a0 - 1 : 0) * w;
    int r1 = (2 * a0) * w;
    int r2 = (2 * a0 + 1) * w;
    int r3 = (fpv ? 2 * a0 + 2 : 2 * a0 + 1) * w;
    int cL = um ? 2 * b0 - 2 : 0;   // aligned float2 covering cols 2b0-2,2b0-1
    int cM = 2 * b0;                // cols 2b0, 2b0+1
    int cR = up ? 2 * b0 + 2 : 0;   // cols 2b0+2, 2b0+3

    float acc[2][2][2][2];  // [sr][sc][dy][dx]
#pragma unroll
    for (int i = 0; i < 2; ++i)
#pragma unroll
        for (int j = 0; j < 2; ++j)
#pragma unroll
            for (int k = 0; k < 2; ++k)
#pragma unroll
                for (int l = 0; l < 2; ++l) acc[i][j][k][l] = 0.f;

    auto do_channel = [&](const float* __restrict__ src, const float* __restrict__ F) {
        float P[4][4];
        const int ro[4] = {r0, r1, r2, r3};
        const float rm[4] = {fm, 1.f, 1.f, fp_};
#pragma unroll
        for (int r = 0; r < 4; ++r) {
            const float* base = src + ro[r];
            float2 L = *(const float2*)(base + cL);
            float2 M = *(const float2*)(base + cM);
            float2 R = *(const float2*)(base + cR);
            float mask = rm[r];
            P[r][0] = (um ? L.y : 0.f) * mask;
            P[r][1] = M.x * mask;
            P[r][2] = M.y * mask;
            P[r][3] = (up ? R.x : 0.f) * mask;
        }
        // site (sr,sc): output (2p+dy, 2q+dx) += P[sr+a][sc+b] * F[(4+dy-2a)*5 + (4+dx-2b)]
#pragma unroll
        for (int a = 0; a < 3; ++a) {
#pragma unroll
            for (int b = 0; b < 3; ++b) {
                float w00 = F[(4 - 2 * a) * 5 + (4 - 2 * b)];
                float w01 = (b >= 1) ? F[(4 - 2 * a) * 5 + (5 - 2 * b)] : 0.f;
                float w10 = (a >= 1) ? F[(5 - 2 * a) * 5 + (4 - 2 * b)] : 0.f;
                float w11 = (a >= 1 && b >= 1) ? F[(5 - 2 * a) * 5 + (5 - 2 * b)] : 0.f;
#pragma unroll
                for (int sr = 0; sr < 2; ++sr) {
#pragma unroll
                    for (int sc = 0; sc < 2; ++sc) {
                        float pv = P[sr + a][sc + b];
                        acc[sr][sc][0][0] = fmaf(pv, w00, acc[sr][sc][0][0]);
                        if (b >= 1) acc[sr][sc][0][1] = fmaf(pv, w01, acc[sr][sc][0][1]);
                        if (a >= 1) acc[sr][sc][1][0] = fmaf(pv, w10, acc[sr][sc][1][0]);
                        if (a >= 1 && b >= 1)
                                    acc[sr][sc][1][1] = fmaf(pv, w11, acc[sr][sc][1][1]);
                    }
                }
            }
        }
    };

    do_channel(rp, filt);
#pragma unroll
    for (int c = 1; c < NORIENT; ++c)
        do_channel(cp + (long)c * cs, filt + c * 25);

    int OW = w << 1;
    long ob = (long)n * 4 * (long)cs + (long)(4 * a0) * OW + 4 * b0;
    *(float4*)(out + ob)          = make_float4(acc[0][0][0][0], acc[0][0][0][1],
                                                acc[0][1][0][0], acc[0][1][0][1]);
    *(float4*)(out + ob + OW)     = make_float4(acc[0][0][1][0], acc[0][0][1][1],
                                                acc[0][1][1][0], acc[0][1][1][1]);
    *(float4*)(out + ob + 2 * OW) = make_float4(acc[1][0][0][0], acc[1][0][0][1],
                                                acc[1][1][0][0], acc[1][1][0][1]);
    *(float4*)(out + ob + 3 * OW) = make_float4(acc[1][0][1][0], acc[1][0][1][1],
                                                acc[1][1][1][0], acc[1][1][1][1]);
}

extern "C" void kernel_launch(void* const* d_in, const int* in_sizes, int n_in,
                              void* d_out, int out_size, void* d_ws, size_t ws_size,
                              hipStream_t stream) {
    const float* x     = (const float*)d_in[0];
    const float* fwd_f = (const float*)d_in[1];
    const float* inv_f = (const float*)d_in[2];
    float* out = (float*)d_out;
    float* ws  = (float*)d_ws;

    const int N = 32;

    // workspace layout (floats) — all offsets multiples of 4 -> 16B aligned
    float* l4 = ws;                  // 32*8*256*256 = 16,777,216
    float* l3 = l4 + 16777216;       // 32*8*128*128 =  4,194,304
    float* l2 = l3 + 4194304;        // 32*8*64*64   =  1,048,576
    float* l1 = l2 + 1048576;        // 32*8*32*32   =    262,144
    float* r1 = l1 + 262144;         // 32*64*64     =    131,072
    float* r2 = r1 + 131072;         // 32*128*128   =    524,288
    float* r3 = r2 + 524288;         // 32*256*256   =  2,097,152

    dim3 blk(256);
    auto nblocks = [](long total) { return dim3((unsigned)((total + 255) / 256)); };

    // ---- forward transform (threads = N * OH/2 * OW/2) ----
    fwd_conv_kernel<<<nblocks(32L * 128 * 128), blk, 0, stream>>>(
        x, 512L * 512, fwd_f, l4, 512, 512, 256, 256, N);
    fwd_conv_kernel<<<nblocks(32L * 64 * 64), blk, 0, stream>>>(
        l4, 8L * 256 * 256, fwd_f, l3, 256, 256, 128, 128, N);
    fwd_conv_kernel<<<nblocks(32L * 32 * 32), blk, 0, stream>>>(
        l3, 8L * 128 * 128, fwd_f, l2, 128, 128, 64, 64, N);
    fwd_conv_kernel<<<nblocks(32L * 16 * 16), blk, 0, stream>>>(
        l2, 8L * 64 * 64, fwd_f, l1, 64, 64, 32, 32, N);

    // ---- inverse transform (threads = N * h/2 * w/2) ----
    inv_tconv_kernel<<<nblocks(32L * 16 * 16), blk, 0, stream>>>(
        l1, 8L * 32 * 32, l1, inv_f, r1, 32, 32, N);
    inv_tconv_kernel<<<nblocks(32L * 32 * 32), blk, 0, stream>>>(
        r1, 64L * 64, l2, inv_f, r2, 64, 64, N);
    inv_tconv_kernel<<<nblocks(32L * 64 * 64), blk, 0, stream>>>(
        r2, 128L * 128, l3, inv_f, r3, 128, 128, N);
    inv_tconv_kernel<<<nblocks(32L * 128 * 128), blk, 0, stream>>>(
        r3, 256L * 256, l4, inv_f, out, 256, 256, N);
}